// Round 4
// baseline (1612.256 us; speedup 1.0000x reference)
//
#include <hip/hip_runtime.h>
#include <cstdint>
#include <cstddef>

#define DEV __device__ __forceinline__

typedef unsigned short u16;
typedef unsigned int   u32;
typedef __attribute__((ext_vector_type(8))) short bf16x8;
typedef __attribute__((ext_vector_type(4))) float f32x4;

static constexpr int NROWS = 50000;
static constexpr int FEAT  = 2048;
static constexpr int HID   = 1024;
static constexpr int DATT  = 512;
static constexpr int TXTD  = 768;

// ---------- helpers ----------
DEV u32 bfbits(float f) {                      // fp32 -> bf16 bits, round-to-nearest-even
  u32 u = __float_as_uint(f);
  return (u + 0x7fffu + ((u >> 16) & 1u)) >> 16;
}
DEV u32 pk2(float lo, float hi) { return bfbits(lo) | (bfbits(hi) << 16); }
DEV float bflo(u32 u) { return __uint_as_float(u << 16); }
DEV float bfhi(u32 u) { return __uint_as_float(u & 0xffff0000u); }

// async global->LDS, 16B per lane; lds dst is WAVE-UNIFORM base (HW adds lane*16)
DEV void gld_lds16(const u16* g, u16* l) {
  __builtin_amdgcn_global_load_lds(
      (const __attribute__((address_space(1))) unsigned int*)g,
      (__attribute__((address_space(3))) unsigned int*)l, 16, 0, 0);
}

// ---------- K1a: W1 [FEAT][HID] -> bf16 W1T [HID][FEAT] ----------
__global__ void k_t_w1(const float* __restrict__ W, u16* __restrict__ out) {
  __shared__ float tile[64][65];
  const int KT = FEAT / 64;                    // 32
  int bid = blockIdx.x;
  int kt = bid % KT, nt = bid / KT;
  int k0 = kt * 64, n0 = nt * 64;
  int t = threadIdx.x;
#pragma unroll
  for (int i = 0; i < 16; i++) {
    int idx = t + i * 256;
    int kk = idx >> 6, nn = idx & 63;
    tile[kk][nn] = W[(size_t)(k0 + kk) * HID + n0 + nn];
  }
  __syncthreads();
#pragma unroll
  for (int i = 0; i < 16; i++) {
    int idx = t + i * 256;
    int nn = idx >> 6, kk = idx & 63;
    out[(size_t)(n0 + nn) * FEAT + k0 + kk] = (u16)bfbits(tile[kk][nn]);
  }
}

// ---------- K1b: interleave Wa|Wb [HID][DATT] -> bf16 WgT [2*DATT][HID] ----------
// output row n: n=2j -> Wa[:,j], n=2j+1 -> Wb[:,j]
__global__ void k_t_wab(const float* __restrict__ Wa, const float* __restrict__ Wb,
                        u16* __restrict__ out) {
  __shared__ float tile[64][65];
  const int KT = HID / 64;                     // 16
  int bid = blockIdx.x;
  int kt = bid % KT, nt = bid / KT;
  int k0 = kt * 64, n0 = nt * 64;
  int t = threadIdx.x;
#pragma unroll
  for (int i = 0; i < 16; i++) {
    int idx = t + i * 256;
    int kk = idx >> 6, nn = idx & 63;
    int n = n0 + nn;
    const float* src = (n & 1) ? Wb : Wa;
    tile[kk][nn] = src[(size_t)(k0 + kk) * DATT + (n >> 1)];
  }
  __syncthreads();
#pragma unroll
  for (int i = 0; i < 16; i++) {
    int idx = t + i * 256;
    int nn = idx >> 6, kk = idx & 63;
    out[(size_t)(n0 + nn) * HID + k0 + kk] = (u16)bfbits(tile[kk][nn]);
  }
}

// ---------- shared MFMA tile compute: 128x128 tile, BK=64, 4 waves x (64x64) ----------
// LDS layout per operand: [row 0..127][64 k bf16 = 8 x 16B slots], slot XOR-swizzled by (row&7)
DEV void tile_mfma(const char* bufA, const char* bufB, f32x4 acc[4][4],
                   int lo, int hi, int wr, int wc) {
#pragma unroll
  for (int ks = 0; ks < 2; ks++) {
    bf16x8 av[4], bv[4];
#pragma unroll
    for (int m = 0; m < 4; m++) {
      int row = wr * 64 + m * 16 + lo;
      int off = (row * 128 + ks * 64 + hi * 16) ^ ((row & 7) << 4);
      av[m] = *(const bf16x8*)(bufA + off);
    }
#pragma unroll
    for (int n = 0; n < 4; n++) {
      int col = wc * 64 + n * 16 + lo;
      int off = (col * 128 + ks * 64 + hi * 16) ^ ((col & 7) << 4);
      bv[n] = *(const bf16x8*)(bufB + off);
    }
#pragma unroll
    for (int m = 0; m < 4; m++)
#pragma unroll
      for (int n = 0; n < 4; n++)
        acc[m][n] = __builtin_amdgcn_mfma_f32_16x16x32_bf16(av[m], bv[n], acc[m][n], 0, 0, 0);
  }
}

// ---------- GEMM1: Hb = relu(x @ W1 + b1) in bf16 ----------
// m97-replica: single 32KB LDS buffer, 2 barriers/K-step, 4-5 blocks/CU co-resident.
// A (x, fp32): reg-staged with fused fp32->bf16 convert, swizzled ds_write.
// B (W1T, bf16): global_load_lds direct, swizzle folded into per-lane SOURCE addr.
__global__ __launch_bounds__(256, 4) void k_gemm1(const float* __restrict__ X,
                                                  const u16* __restrict__ BT,
                                                  const float* __restrict__ b1,
                                                  u16* __restrict__ Hb) {
  __shared__ __align__(16) char smem[32768];      // A 16KB | B 16KB
  int t = threadIdx.x;
  int l = t & 63, w = t >> 6;
  int lo = l & 15, hi = l >> 4;
  int wr = w >> 1, wc = w & 1;

  int nwg = gridDim.x, bid = blockIdx.x;
  int li = ((nwg & 7) == 0) ? ((bid & 7) * (nwg >> 3) + (bid >> 3)) : bid;  // XCD swizzle
  int mt = li >> 3, nt = li & 7;                   // nt-minor: A-panel reuse within XCD L2
  int rowbase = mt * 128, ncb0 = nt * 128;

  f32x4 acc[4][4];
#pragma unroll
  for (int m = 0; m < 4; m++)
#pragma unroll
    for (int n = 0; n < 4; n++) acc[m][n] = {0.f, 0.f, 0.f, 0.f};

  const int KT = FEAT / 64;                        // 32

  // ---- K-invariant staging addresses (hoisted out of the loop) ----
  int r0 = t >> 3;                                 // 0..31
  int k8a = t & 7;                                 // A source slot (linear)
  int swzA = (r0 & 7) << 4;                        // row&7 invariant across i (+32 rows)
  int k8b = (t & 7) ^ (r0 & 7);                    // B source slot (inverse-swizzled)
  const float* pA[4];
  const u16*   pB[4];
  int offA[4];
  u16* dstB[4];
#pragma unroll
  for (int i = 0; i < 4; i++) {
    int row = r0 + i * 32;
    int grow = rowbase + row; if (grow >= NROWS) grow = NROWS - 1;
    pA[i] = X + (size_t)grow * FEAT + k8a * 8;
    offA[i] = (row * 128 + k8a * 16) ^ swzA;       // row*128 already spans i (bugfix)
    pB[i] = BT + (size_t)(ncb0 + row) * FEAT + k8b * 8;
    dstB[i] = (u16*)(smem + 16384 + i * 4096 + w * 1024);
  }

  auto stage = [&](int kt_) {
    int kbase = kt_ * 64;
#pragma unroll
    for (int i = 0; i < 4; i++)                    // B first: async, fire-and-forget
      gld_lds16(pB[i] + kbase, dstB[i]);
#pragma unroll
    for (int i = 0; i < 4; i++) {                  // A: load fp32, cvt, swizzled ds_write
      const float4* src = (const float4*)(pA[i] + kbase);
      float4 f0 = src[0], f1 = src[1];
      uint4 v; v.x = pk2(f0.x, f0.y); v.y = pk2(f0.z, f0.w);
      v.z = pk2(f1.x, f1.y); v.w = pk2(f1.z, f1.w);
      *(uint4*)(smem + offA[i]) = v;
    }
  };

  stage(0);
  __syncthreads();
  for (int kt_ = 0; kt_ < KT; ++kt_) {
    tile_mfma(smem, smem + 16384, acc, lo, hi, wr, wc);
    __syncthreads();                               // all waves done reading buf
    if (kt_ + 1 < KT) {
      stage(kt_ + 1);
      __syncthreads();                             // staging (incl. vmcnt drain) complete
    }
  }

  int mrow0 = rowbase + wr * 64;
  int ncol0 = ncb0 + wc * 64;
#pragma unroll
  for (int n = 0; n < 4; n++) {
    int col = ncol0 + n * 16 + lo;
    float bias = b1[col];
#pragma unroll
    for (int m = 0; m < 4; m++)
#pragma unroll
      for (int i = 0; i < 4; i++) {
        int row = mrow0 + m * 16 + hi * 4 + i;
        if (row < NROWS) {
          float v = acc[m][n][i] + bias;
          v = fmaxf(v, 0.f);
          Hb[(size_t)row * HID + col] = (u16)bfbits(v);
        }
      }
  }
}

// ---------- GEMM2: scores[r] += sum_j tanh(h@Wa+ba)*sigmoid(h@Wb+bb)*Wc ----------
// Both operands bf16 -> both via global_load_lds with source-folded swizzle. Single buffer.
__global__ __launch_bounds__(256, 4) void k_gemm2(const u16* __restrict__ Hb,
                                                  const u16* __restrict__ BT,
                                                  const float* __restrict__ ba,
                                                  const float* __restrict__ bb,
                                                  const float* __restrict__ Wc,
                                                  float* __restrict__ scores) {
  __shared__ __align__(16) char smem[32768];
  int t = threadIdx.x;
  int l = t & 63, w = t >> 6;
  int lo = l & 15, hi = l >> 4;
  int wr = w >> 1, wc_ = w & 1;

  int nwg = gridDim.x, bid = blockIdx.x;
  int li = ((nwg & 7) == 0) ? ((bid & 7) * (nwg >> 3) + (bid >> 3)) : bid;
  int mt = li >> 3, nt = li & 7;                   // N = 1024 interleaved a|g cols
  int rowbase = mt * 128, ncb0 = nt * 128;

  f32x4 acc[4][4];
#pragma unroll
  for (int m = 0; m < 4; m++)
#pragma unroll
    for (int n = 0; n < 4; n++) acc[m][n] = {0.f, 0.f, 0.f, 0.f};

  const int KT = HID / 64;                         // 16

  // ---- K-invariant staging addresses ----
  int r0 = t >> 3;
  int k8 = (t & 7) ^ (r0 & 7);                     // inverse-swizzled source slot
  const u16* pA[4];
  const u16* pB[4];
  u16* dstA[4];
  u16* dstB[4];
#pragma unroll
  for (int i = 0; i < 4; i++) {
    int row = r0 + i * 32;
    int grow = rowbase + row; if (grow >= NROWS) grow = NROWS - 1;
    pA[i] = Hb + (size_t)grow * HID + k8 * 8;
    pB[i] = BT + (size_t)(ncb0 + row) * HID + k8 * 8;
    dstA[i] = (u16*)(smem + i * 4096 + w * 1024);
    dstB[i] = (u16*)(smem + 16384 + i * 4096 + w * 1024);
  }

  auto stage = [&](int kt_) {
    int kbase = kt_ * 64;
#pragma unroll
    for (int i = 0; i < 4; i++) {
      gld_lds16(pA[i] + kbase, dstA[i]);
      gld_lds16(pB[i] + kbase, dstB[i]);
    }
  };

  stage(0);
  __syncthreads();
  for (int kt_ = 0; kt_ < KT; ++kt_) {
    tile_mfma(smem, smem + 16384, acc, lo, hi, wr, wc_);
    __syncthreads();
    if (kt_ + 1 < KT) {
      stage(kt_ + 1);
      __syncthreads();
    }
  }

  // fused gated-attention epilogue
  int mrow0 = rowbase + wr * 64;
  int ncol0 = ncb0 + wc_ * 64;
  float rs[4][4];
#pragma unroll
  for (int m = 0; m < 4; m++)
#pragma unroll
    for (int i = 0; i < 4; i++) rs[m][i] = 0.f;

#pragma unroll
  for (int n = 0; n < 4; n++) {
    int col = ncol0 + n * 16 + lo;
    int j = col >> 1;
    bool odd = (col & 1);                          // even col -> tanh branch, odd -> sigmoid
    float bias = odd ? bb[j] : ba[j];
    float wcj = Wc[j];
    float scl  = odd ? 0.5f : 1.0f;                // sigmoid(v) = 0.5*tanh(v/2)+0.5
    float pmul = odd ? 0.5f : 1.0f;
    float padd = odd ? 0.5f : 0.0f;
#pragma unroll
    for (int m = 0; m < 4; m++)
#pragma unroll
      for (int i = 0; i < 4; i++) {
        float v = acc[m][n][i] + bias;
        float act = fmaf(tanhf(v * scl), pmul, padd);
        float prt = __shfl_xor(act, 1);            // partner activation (paired column)
        rs[m][i] = fmaf(act * prt, wcj, rs[m][i]);
      }
  }
#pragma unroll
  for (int m = 0; m < 4; m++)
#pragma unroll
    for (int i = 0; i < 4; i++) {
      float sv = rs[m][i];
      sv += __shfl_xor(sv, 2);
      sv += __shfl_xor(sv, 4);
      sv += __shfl_xor(sv, 8);                     // even lanes cover each pair exactly once
      if (lo == 0) {
        int row = mrow0 + m * 16 + hi * 4 + i;
        if (row < NROWS) atomicAdd(&scores[row], sv);
      }
    }
}

// ---------- softmax reductions ----------
__global__ void k_red1(const float* __restrict__ s, int n, float2* __restrict__ part) {
  __shared__ float sm[256];
  int t = threadIdx.x;
  int stride = gridDim.x * 256;
  float m = -3.4e38f;
  for (int i = blockIdx.x * 256 + t; i < n; i += stride) m = fmaxf(m, s[i]);
  sm[t] = m; __syncthreads();
  for (int st = 128; st; st >>= 1) { if (t < st) sm[t] = fmaxf(sm[t], sm[t + st]); __syncthreads(); }
  float bm = sm[0];
  __syncthreads();
  float se = 0.f;
  for (int i = blockIdx.x * 256 + t; i < n; i += stride) se += expf(s[i] - bm);
  sm[t] = se; __syncthreads();
  for (int st = 128; st; st >>= 1) { if (t < st) sm[t] += sm[t + st]; __syncthreads(); }
  if (t == 0) part[blockIdx.x] = make_float2(bm, sm[0]);
}

__global__ void k_red2(const float2* __restrict__ part, float* __restrict__ red2) {
  int t = threadIdx.x;                             // 64 threads = 1 wave
  float2 p = part[t];
  float m = p.x;
#pragma unroll
  for (int off = 32; off; off >>= 1) m = fmaxf(m, __shfl_down(m, off));
  m = __shfl(m, 0);
  float se = p.y * expf(p.x - m);
#pragma unroll
  for (int off = 32; off; off >>= 1) se += __shfl_down(se, off);
  if (t == 0) { red2[0] = m; red2[1] = se; }
}

// ---------- pooled M = softmax(scores) @ h ----------
__global__ void k_pool(const u16* __restrict__ Hb, const float* __restrict__ scores,
                       const float* __restrict__ red2, float* __restrict__ Mpool) {
  int t = threadIdx.x;
  int c = t * 4;
  float gmax = red2[0];
  float ginv = 1.0f / red2[1];
  float a0 = 0, a1 = 0, a2 = 0, a3 = 0;
  int r0 = blockIdx.x * 128;
  int rend = r0 + 128; if (rend > NROWS) rend = NROWS;
  for (int r = r0; r < rend; ++r) {
    float wgt = expf(scores[r] - gmax) * ginv;
    uint2 hv = *(const uint2*)(Hb + (size_t)r * HID + c);
    a0 = fmaf(wgt, bflo(hv.x), a0);
    a1 = fmaf(wgt, bfhi(hv.x), a1);
    a2 = fmaf(wgt, bflo(hv.y), a2);
    a3 = fmaf(wgt, bfhi(hv.y), a3);
  }
  atomicAdd(&Mpool[c + 0], a0);
  atomicAdd(&Mpool[c + 1], a1);
  atomicAdd(&Mpool[c + 2], a2);
  atomicAdd(&Mpool[c + 3], a3);
}

// ---------- text branch + logits ----------
__global__ void k_final(const float* __restrict__ Mpool, const float* __restrict__ text,
                        const float* __restrict__ Wt, const float* __restrict__ bt,
                        const float* __restrict__ Wcls, const float* __restrict__ bcls,
                        float* __restrict__ out) {
  __shared__ float Mv[HID];
  __shared__ float red0[256], red1[256];
  int t = threadIdx.x;
#pragma unroll
  for (int rep = 0; rep < 4; rep++) {
    int n = t + rep * 256;
    float accv = bt[n];
    for (int k = 0; k < TXTD; k++) accv = fmaf(text[k], Wt[(size_t)k * HID + n], accv);
    accv = fmaxf(accv, 0.f);
    Mv[n] = Mpool[n] + accv;
  }
  __syncthreads();
  float p0 = 0.f, p1 = 0.f;
#pragma unroll
  for (int rep = 0; rep < 4; rep++) {
    int n = t + rep * 256;
    p0 = fmaf(Mv[n], Wcls[n * 2 + 0], p0);
    p1 = fmaf(Mv[n], Wcls[n * 2 + 1], p1);
  }
  red0[t] = p0; red1[t] = p1;
  __syncthreads();
  for (int st = 128; st; st >>= 1) {
    if (t < st) { red0[t] += red0[t + st]; red1[t] += red1[t + st]; }
    __syncthreads();
  }
  if (t == 0) { out[0] = red0[0] + bcls[0]; out[1] = red1[0] + bcls[1]; }
}

// ---------- launch ----------
extern "C" void kernel_launch(void* const* d_in, const int* in_sizes, int n_in,
                              void* d_out, int out_size, void* d_ws, size_t ws_size,
                              hipStream_t stream) {
  const float* x    = (const float*)d_in[0];
  const float* text = (const float*)d_in[1];
  const float* W1   = (const float*)d_in[2];
  const float* b1   = (const float*)d_in[3];
  const float* Wa   = (const float*)d_in[4];
  const float* ba   = (const float*)d_in[5];
  const float* Wb   = (const float*)d_in[6];
  const float* bb   = (const float*)d_in[7];
  const float* Wc   = (const float*)d_in[8];
  // d_in[9] = bc: uniform shift on pre-softmax scores -> dropped (softmax invariant)
  const float* Wt   = (const float*)d_in[10];
  const float* bt   = (const float*)d_in[11];
  const float* Wcls = (const float*)d_in[12];
  const float* bcls = (const float*)d_in[13];

  // workspace layout (bytes)
  const size_t off_w1t = 0;                          // 1024*2048*2 = 4,194,304
  const size_t off_wg  = 4194304;                    // 1024*1024*2 = 2,097,152
  const size_t off_hb  = 6291456;                    // 50000*1024*2 = 102,400,000
  const size_t off_sc  = 108691456;                  // 50000*4
  const size_t off_pt  = 108891456;                  // 64*8
  const size_t off_r2  = 108891968;                  // 8
  const size_t off_m   = 108892032;                  // 1024*4
  const size_t NEED    = 108896128;
  if (ws_size < NEED) return;

  char* ws = (char*)d_ws;
  u16*   W1T    = (u16*)(ws + off_w1t);
  u16*   WgT    = (u16*)(ws + off_wg);
  u16*   Hb     = (u16*)(ws + off_hb);
  float* scores = (float*)(ws + off_sc);
  float2* part  = (float2*)(ws + off_pt);
  float* red2   = (float*)(ws + off_r2);
  float* Mpool  = (float*)(ws + off_m);

  hipMemsetAsync(scores, 0, NROWS * sizeof(float), stream);
  hipMemsetAsync(Mpool, 0, HID * sizeof(float), stream);

  k_t_w1 <<<(FEAT / 64) * (HID / 64), 256, 0, stream>>>(W1, W1T);
  k_t_wab<<<(HID / 64) * (HID / 64),  256, 0, stream>>>(Wa, Wb, WgT);

  const int MT = (NROWS + 127) / 128;                // 391
  k_gemm1<<<MT * 8, 256, 0, stream>>>(x, W1T, b1, Hb);
  k_gemm2<<<MT * 8, 256, 0, stream>>>(Hb, WgT, ba, bb, Wc, scores);

  k_red1<<<64, 256, 0, stream>>>(scores, NROWS, part);
  k_red2<<<1, 64, 0, stream>>>(part, red2);
  k_pool<<<MT, 256, 0, stream>>>(Hb, scores, red2, Mpool);
  k_final<<<1, 256, 0, stream>>>(Mpool, text, Wt, bt, Wcls, bcls, (float*)d_out);
}

// Round 6
// 1138.858 us; speedup vs baseline: 1.4157x; 1.4157x over previous
//
#include <hip/hip_runtime.h>
#include <cstdint>
#include <cstddef>

#define DEV __device__ __forceinline__

typedef unsigned short u16;
typedef unsigned int   u32;
typedef __attribute__((ext_vector_type(8))) short bf16x8;
typedef __attribute__((ext_vector_type(4))) float f32x4;

static constexpr int NROWS = 50000;
static constexpr int FEAT  = 2048;
static constexpr int HID   = 1024;
static constexpr int DATT  = 512;
static constexpr int TXTD  = 768;

// ---------- helpers ----------
DEV u32 bfbits(float f) {                      // fp32 -> bf16 bits, round-to-nearest-even
  u32 u = __float_as_uint(f);
  return (u + 0x7fffu + ((u >> 16) & 1u)) >> 16;
}
DEV u32 pk2(float lo, float hi) { return bfbits(lo) | (bfbits(hi) << 16); }
DEV float bflo(u32 u) { return __uint_as_float(u << 16); }
DEV float bfhi(u32 u) { return __uint_as_float(u & 0xffff0000u); }

// async global->LDS, 16B per lane; lds dst is WAVE-UNIFORM base (HW adds lane*16)
DEV void gld_lds16(const u16* g, u16* l) {
  __builtin_amdgcn_global_load_lds(
      (const __attribute__((address_space(1))) unsigned int*)g,
      (__attribute__((address_space(3))) unsigned int*)l, 16, 0, 0);
}

// ---------- K1a: W1 [FEAT][HID] -> bf16 W1T [HID][FEAT] ----------
__global__ void k_t_w1(const float* __restrict__ W, u16* __restrict__ out) {
  __shared__ float tile[64][65];
  const int KT = FEAT / 64;                    // 32
  int bid = blockIdx.x;
  int kt = bid % KT, nt = bid / KT;
  int k0 = kt * 64, n0 = nt * 64;
  int t = threadIdx.x;
#pragma unroll
  for (int i = 0; i < 16; i++) {
    int idx = t + i * 256;
    int kk = idx >> 6, nn = idx & 63;
    tile[kk][nn] = W[(size_t)(k0 + kk) * HID + n0 + nn];
  }
  __syncthreads();
#pragma unroll
  for (int i = 0; i < 16; i++) {
    int idx = t + i * 256;
    int nn = idx >> 6, kk = idx & 63;
    out[(size_t)(n0 + nn) * FEAT + k0 + kk] = (u16)bfbits(tile[kk][nn]);
  }
}

// ---------- K1b: interleave Wa|Wb [HID][DATT] -> bf16 WgT [2*DATT][HID] ----------
// output row n: n=2j -> Wa[:,j], n=2j+1 -> Wb[:,j]
__global__ void k_t_wab(const float* __restrict__ Wa, const float* __restrict__ Wb,
                        u16* __restrict__ out) {
  __shared__ float tile[64][65];
  const int KT = HID / 64;                     // 16
  int bid = blockIdx.x;
  int kt = bid % KT, nt = bid / KT;
  int k0 = kt * 64, n0 = nt * 64;
  int t = threadIdx.x;
#pragma unroll
  for (int i = 0; i < 16; i++) {
    int idx = t + i * 256;
    int kk = idx >> 6, nn = idx & 63;
    int n = n0 + nn;
    const float* src = (n & 1) ? Wb : Wa;
    tile[kk][nn] = src[(size_t)(k0 + kk) * DATT + (n >> 1)];
  }
  __syncthreads();
#pragma unroll
  for (int i = 0; i < 16; i++) {
    int idx = t + i * 256;
    int nn = idx >> 6, kk = idx & 63;
    out[(size_t)(n0 + nn) * HID + k0 + kk] = (u16)bfbits(tile[kk][nn]);
  }
}

// ---------- MFMA micro-step: BK=32, dense LDS layout [row][32 bf16 = 64B] ----------
DEV void mfma_step32(const char* smA, const char* smB, f32x4 acc[4][4],
                     int lo, int hi, int wr, int wc) {
  bf16x8 av[4], bv[4];
#pragma unroll
  for (int m = 0; m < 4; m++) {
    int row = wr * 64 + m * 16 + lo;
    av[m] = *(const bf16x8*)(smA + row * 64 + hi * 16);   // dense 1KB per frag set
  }
#pragma unroll
  for (int n = 0; n < 4; n++) {
    int col = wc * 64 + n * 16 + lo;
    bv[n] = *(const bf16x8*)(smB + col * 64 + hi * 16);
  }
#pragma unroll
  for (int m = 0; m < 4; m++)
#pragma unroll
    for (int n = 0; n < 4; n++)
      acc[m][n] = __builtin_amdgcn_mfma_f32_16x16x32_bf16(av[m], bv[n], acc[m][n], 0, 0, 0);
}

// ---------- GEMM1: Hb = relu(x @ W1 + b1) in bf16 ----------
// m97 geometry: 128x128 tile, BK=32, single 16KB LDS buffer, 2 barriers/K-step.
// A (fp32): T14 issue-early reg-stage (load k+1 before MFMA k; cvt+ds_write after barrier).
// B (bf16): global_load_lds, linear both sides (dense layout needs no swizzle).
__global__ __launch_bounds__(256, 4) void k_gemm1(const float* __restrict__ X,
                                                  const u16* __restrict__ BT,
                                                  const float* __restrict__ b1,
                                                  u16* __restrict__ Hb) {
  __shared__ __align__(16) char smem[16384];      // A 8KB | B 8KB
  char* smA = smem;
  char* smB = smem + 8192;
  int t = threadIdx.x;
  int l = t & 63, w = t >> 6;
  int lo = l & 15, hi = l >> 4;
  int wr = w >> 1, wc = w & 1;

  int nwg = gridDim.x, bid = blockIdx.x;
  int li = ((nwg & 7) == 0) ? ((bid & 7) * (nwg >> 3) + (bid >> 3)) : bid;  // XCD swizzle
  int mt = li >> 3, nt = li & 7;                   // nt-minor: A-panel L2 reuse
  int rowbase = mt * 128, ncb0 = nt * 128;

  f32x4 acc[4][4];
#pragma unroll
  for (int m = 0; m < 4; m++)
#pragma unroll
    for (int n = 0; n < 4; n++) acc[m][n] = {0.f, 0.f, 0.f, 0.f};

  const int KT = FEAT / 32;                        // 64

  // A fp32 tile 128x32 = 16KB: 4 x float4 per thread. row = s>>3, slot = s&7.
  const float* pA[4];
  int ldsA[4];
#pragma unroll
  for (int i = 0; i < 4; i++) {
    int s = t + i * 256;
    int row = s >> 3, sl = s & 7;
    int grow = rowbase + row; if (grow >= NROWS) grow = NROWS - 1;
    pA[i] = X + (size_t)grow * FEAT + sl * 4;
    ldsA[i] = row * 64 + sl * 8;                   // bf16 byte offset (dense)
  }
  // B bf16 tile 128x32 = 8KB: 2 x gld_lds16 per thread. row = s>>2, slot = s&3.
  const u16* pB[2];
  u16* dstB[2];
#pragma unroll
  for (int i = 0; i < 2; i++) {
    int s = t + i * 256;
    int nn = s >> 2, sl = s & 3;
    pB[i] = BT + (size_t)(ncb0 + nn) * FEAT + sl * 8;
    dstB[i] = (u16*)(smB + i * 4096 + w * 1024);   // wave-uniform linear dest
  }

  float4 ar[4];
  auto loadA = [&](int kt_) {
    int kb = kt_ * 32;
#pragma unroll
    for (int i = 0; i < 4; i++) ar[i] = *(const float4*)(pA[i] + kb);
  };
  auto writeA = [&]() {
#pragma unroll
    for (int i = 0; i < 4; i++) {
      uint2 v; v.x = pk2(ar[i].x, ar[i].y); v.y = pk2(ar[i].z, ar[i].w);
      *(uint2*)(smA + ldsA[i]) = v;
    }
  };
  auto stageB = [&](int kt_) {
    int kb = kt_ * 32;
#pragma unroll
    for (int i = 0; i < 2; i++) gld_lds16(pB[i] + kb, dstB[i]);
  };

  // prologue
  loadA(0);
  stageB(0);
  writeA();
  __syncthreads();                                 // drains vmcnt (gld_lds) + lgkm

  for (int kt_ = 0; kt_ < KT; ++kt_) {
    bool more = (kt_ + 1 < KT);
    if (more) loadA(kt_ + 1);                      // issue early: in flight under MFMA
    mfma_step32(smA, smB, acc, lo, hi, wr, wc);
    __syncthreads();                               // all waves done reading tile kt
    if (more) {
      stageB(kt_ + 1);                             // async B into LDS
      writeA();                                    // A regs (latency already elapsed)
      __syncthreads();                             // tile kt+1 ready
    }
  }

  int mrow0 = rowbase + wr * 64;
  int ncol0 = ncb0 + wc * 64;
#pragma unroll
  for (int n = 0; n < 4; n++) {
    int col = ncol0 + n * 16 + lo;
    float bias = b1[col];
#pragma unroll
    for (int m = 0; m < 4; m++)
#pragma unroll
      for (int i = 0; i < 4; i++) {
        int row = mrow0 + m * 16 + hi * 4 + i;
        if (row < NROWS) {
          float v = acc[m][n][i] + bias;
          v = fmaxf(v, 0.f);
          Hb[(size_t)row * HID + col] = (u16)bfbits(v);
        }
      }
  }
}

// ---------- GEMM2: scores[r] += sum_j tanh(h@Wa+ba)*sigmoid(h@Wb+bb)*Wc ----------
// Both operands bf16 via global_load_lds; BK=32 single-buffer m97 loop.
__global__ __launch_bounds__(256, 4) void k_gemm2(const u16* __restrict__ Hb,
                                                  const u16* __restrict__ BT,
                                                  const float* __restrict__ ba,
                                                  const float* __restrict__ bb,
                                                  const float* __restrict__ Wc,
                                                  float* __restrict__ scores) {
  __shared__ __align__(16) char smem[16384];
  char* smA = smem;
  char* smB = smem + 8192;
  int t = threadIdx.x;
  int l = t & 63, w = t >> 6;
  int lo = l & 15, hi = l >> 4;
  int wr = w >> 1, wc_ = w & 1;

  int nwg = gridDim.x, bid = blockIdx.x;
  int li = ((nwg & 7) == 0) ? ((bid & 7) * (nwg >> 3) + (bid >> 3)) : bid;
  int mt = li >> 3, nt = li & 7;                   // N = 1024 interleaved a|g cols
  int rowbase = mt * 128, ncb0 = nt * 128;

  f32x4 acc[4][4];
#pragma unroll
  for (int m = 0; m < 4; m++)
#pragma unroll
    for (int n = 0; n < 4; n++) acc[m][n] = {0.f, 0.f, 0.f, 0.f};

  const int KT = HID / 32;                         // 32

  const u16* pA[2];
  const u16* pB[2];
  u16* dstA[2];
  u16* dstB[2];
#pragma unroll
  for (int i = 0; i < 2; i++) {
    int s = t + i * 256;
    int nn = s >> 2, sl = s & 3;
    int grow = rowbase + nn; if (grow >= NROWS) grow = NROWS - 1;
    pA[i] = Hb + (size_t)grow * HID + sl * 8;
    pB[i] = BT + (size_t)(ncb0 + nn) * HID + sl * 8;
    dstA[i] = (u16*)(smA + i * 4096 + w * 1024);
    dstB[i] = (u16*)(smB + i * 4096 + w * 1024);
  }

  auto stage = [&](int kt_) {
    int kb = kt_ * 32;
#pragma unroll
    for (int i = 0; i < 2; i++) {
      gld_lds16(pA[i] + kb, dstA[i]);
      gld_lds16(pB[i] + kb, dstB[i]);
    }
  };

  stage(0);
  __syncthreads();
  for (int kt_ = 0; kt_ < KT; ++kt_) {
    mfma_step32(smA, smB, acc, lo, hi, wr, wc_);
    __syncthreads();
    if (kt_ + 1 < KT) {
      stage(kt_ + 1);
      __syncthreads();
    }
  }

  // fused gated-attention epilogue
  int mrow0 = rowbase + wr * 64;
  int ncol0 = ncb0 + wc_ * 64;
  float rs[4][4];
#pragma unroll
  for (int m = 0; m < 4; m++)
#pragma unroll
    for (int i = 0; i < 4; i++) rs[m][i] = 0.f;

#pragma unroll
  for (int n = 0; n < 4; n++) {
    int col = ncol0 + n * 16 + lo;
    int j = col >> 1;
    bool odd = (col & 1);                          // even col -> tanh branch, odd -> sigmoid
    float bias = odd ? bb[j] : ba[j];
    float wcj = Wc[j];
    float scl  = odd ? 0.5f : 1.0f;                // sigmoid(v) = 0.5*tanh(v/2)+0.5
    float pmul = odd ? 0.5f : 1.0f;
    float padd = odd ? 0.5f : 0.0f;
#pragma unroll
    for (int m = 0; m < 4; m++)
#pragma unroll
      for (int i = 0; i < 4; i++) {
        float v = acc[m][n][i] + bias;
        float act = fmaf(tanhf(v * scl), pmul, padd);
        float prt = __shfl_xor(act, 1);            // partner activation (paired column)
        rs[m][i] = fmaf(act * prt, wcj, rs[m][i]);
      }
  }
#pragma unroll
  for (int m = 0; m < 4; m++)
#pragma unroll
    for (int i = 0; i < 4; i++) {
      float sv = rs[m][i];
      sv += __shfl_xor(sv, 2);
      sv += __shfl_xor(sv, 4);
      sv += __shfl_xor(sv, 8);                     // even lanes cover each pair exactly once
      if (lo == 0) {
        int row = mrow0 + m * 16 + hi * 4 + i;
        if (row < NROWS) atomicAdd(&scores[row], sv);
      }
    }
}

// ---------- softmax reductions ----------
__global__ void k_red1(const float* __restrict__ s, int n, float2* __restrict__ part) {
  __shared__ float sm[256];
  int t = threadIdx.x;
  int stride = gridDim.x * 256;
  float m = -3.4e38f;
  for (int i = blockIdx.x * 256 + t; i < n; i += stride) m = fmaxf(m, s[i]);
  sm[t] = m; __syncthreads();
  for (int st = 128; st; st >>= 1) { if (t < st) sm[t] = fmaxf(sm[t], sm[t + st]); __syncthreads(); }
  float bm = sm[0];
  __syncthreads();
  float se = 0.f;
  for (int i = blockIdx.x * 256 + t; i < n; i += stride) se += expf(s[i] - bm);
  sm[t] = se; __syncthreads();
  for (int st = 128; st; st >>= 1) { if (t < st) sm[t] += sm[t + st]; __syncthreads(); }
  if (t == 0) part[blockIdx.x] = make_float2(bm, sm[0]);
}

__global__ void k_red2(const float2* __restrict__ part, float* __restrict__ red2) {
  int t = threadIdx.x;                             // 64 threads = 1 wave
  float2 p = part[t];
  float m = p.x;
#pragma unroll
  for (int off = 32; off; off >>= 1) m = fmaxf(m, __shfl_down(m, off));
  m = __shfl(m, 0);
  float se = p.y * expf(p.x - m);
#pragma unroll
  for (int off = 32; off; off >>= 1) se += __shfl_down(se, off);
  if (t == 0) { red2[0] = m; red2[1] = se; }
}

// ---------- pooled M = softmax(scores) @ h ----------
__global__ void k_pool(const u16* __restrict__ Hb, const float* __restrict__ scores,
                       const float* __restrict__ red2, float* __restrict__ Mpool) {
  int t = threadIdx.x;
  int c = t * 4;
  float gmax = red2[0];
  float ginv = 1.0f / red2[1];
  float a0 = 0, a1 = 0, a2 = 0, a3 = 0;
  int r0 = blockIdx.x * 128;
  int rend = r0 + 128; if (rend > NROWS) rend = NROWS;
  for (int r = r0; r < rend; ++r) {
    float wgt = expf(scores[r] - gmax) * ginv;
    uint2 hv = *(const uint2*)(Hb + (size_t)r * HID + c);
    a0 = fmaf(wgt, bflo(hv.x), a0);
    a1 = fmaf(wgt, bfhi(hv.x), a1);
    a2 = fmaf(wgt, bflo(hv.y), a2);
    a3 = fmaf(wgt, bfhi(hv.y), a3);
  }
  atomicAdd(&Mpool[c + 0], a0);
  atomicAdd(&Mpool[c + 1], a1);
  atomicAdd(&Mpool[c + 2], a2);
  atomicAdd(&Mpool[c + 3], a3);
}

// ---------- text branch: Tpart[n] = sum_k text[k]*Wt[k][n] (parallel over k-chunks) ----------
__global__ void k_text(const float* __restrict__ text, const float* __restrict__ Wt,
                       float* __restrict__ Tpart) {
  int b = blockIdx.x;                              // 32 blocks x 24 k-rows
  int t = threadIdx.x;
  float a0 = 0, a1 = 0, a2 = 0, a3 = 0;
  int k0 = b * 24;
  for (int kk = 0; kk < 24; kk++) {
    int k = k0 + kk;
    float tv = text[k];
    const float* wrow = Wt + (size_t)k * HID;
    a0 = fmaf(tv, wrow[t], a0);
    a1 = fmaf(tv, wrow[t + 256], a1);
    a2 = fmaf(tv, wrow[t + 512], a2);
    a3 = fmaf(tv, wrow[t + 768], a3);
  }
  atomicAdd(&Tpart[t], a0);
  atomicAdd(&Tpart[t + 256], a1);
  atomicAdd(&Tpart[t + 512], a2);
  atomicAdd(&Tpart[t + 768], a3);
}

// ---------- final: M = Mpool + relu(Tpart + bt); logits = M @ Wcls + bcls ----------
__global__ void k_final(const float* __restrict__ Mpool, const float* __restrict__ Tpart,
                        const float* __restrict__ bt,
                        const float* __restrict__ Wcls, const float* __restrict__ bcls,
                        float* __restrict__ out) {
  __shared__ float red0[256], red1[256];
  int t = threadIdx.x;
  float p0 = 0.f, p1 = 0.f;
#pragma unroll
  for (int rep = 0; rep < 4; rep++) {
    int n = t + rep * 256;
    float mv = Mpool[n] + fmaxf(Tpart[n] + bt[n], 0.f);
    p0 = fmaf(mv, Wcls[n * 2 + 0], p0);
    p1 = fmaf(mv, Wcls[n * 2 + 1], p1);
  }
  red0[t] = p0; red1[t] = p1;
  __syncthreads();
  for (int st = 128; st; st >>= 1) {
    if (t < st) { red0[t] += red0[t + st]; red1[t] += red1[t + st]; }
    __syncthreads();
  }
  if (t == 0) { out[0] = red0[0] + bcls[0]; out[1] = red1[0] + bcls[1]; }
}

// ---------- launch ----------
extern "C" void kernel_launch(void* const* d_in, const int* in_sizes, int n_in,
                              void* d_out, int out_size, void* d_ws, size_t ws_size,
                              hipStream_t stream) {
  const float* x    = (const float*)d_in[0];
  const float* text = (const float*)d_in[1];
  const float* W1   = (const float*)d_in[2];
  const float* b1   = (const float*)d_in[3];
  const float* Wa   = (const float*)d_in[4];
  const float* ba   = (const float*)d_in[5];
  const float* Wb   = (const float*)d_in[6];
  const float* bb   = (const float*)d_in[7];
  const float* Wc   = (const float*)d_in[8];
  // d_in[9] = bc: uniform shift on pre-softmax scores -> dropped (softmax invariant)
  const float* Wt   = (const float*)d_in[10];
  const float* bt   = (const float*)d_in[11];
  const float* Wcls = (const float*)d_in[12];
  const float* bcls = (const float*)d_in[13];

  // workspace layout (bytes)
  const size_t off_w1t = 0;                          // 1024*2048*2 = 4,194,304
  const size_t off_wg  = 4194304;                    // 1024*1024*2 = 2,097,152
  const size_t off_hb  = 6291456;                    // 50000*1024*2 = 102,400,000
  const size_t off_sc  = 108691456;                  // 50000*4
  const size_t off_pt  = 108891456;                  // 64*8
  const size_t off_r2  = 108891968;                  // 8 (+pad)
  const size_t off_m   = 108892032;                  // 1024*4
  const size_t off_tp  = 108896128;                  // 1024*4
  const size_t NEED    = 108900224;
  if (ws_size < NEED) return;

  char* ws = (char*)d_ws;
  u16*   W1T    = (u16*)(ws + off_w1t);
  u16*   WgT    = (u16*)(ws + off_wg);
  u16*   Hb     = (u16*)(ws + off_hb);
  float* scores = (float*)(ws + off_sc);
  float2* part  = (float2*)(ws + off_pt);
  float* red2   = (float*)(ws + off_r2);
  float* Mpool  = (float*)(ws + off_m);
  float* Tpart  = (float*)(ws + off_tp);

  hipMemsetAsync(scores, 0, NROWS * sizeof(float), stream);
  hipMemsetAsync(Mpool, 0, HID * sizeof(float), stream);
  hipMemsetAsync(Tpart, 0, HID * sizeof(float), stream);

  k_t_w1 <<<(FEAT / 64) * (HID / 64), 256, 0, stream>>>(W1, W1T);
  k_t_wab<<<(HID / 64) * (HID / 64),  256, 0, stream>>>(Wa, Wb, WgT);
  k_text <<<32, 256, 0, stream>>>(text, Wt, Tpart);

  const int MT = (NROWS + 127) / 128;                // 391
  k_gemm1<<<MT * 8, 256, 0, stream>>>(x, W1T, b1, Hb);
  k_gemm2<<<MT * 8, 256, 0, stream>>>(Hb, WgT, ba, bb, Wc, scores);

  k_red1<<<64, 256, 0, stream>>>(scores, NROWS, part);
  k_red2<<<1, 64, 0, stream>>>(part, red2);
  k_pool<<<MT, 256, 0, stream>>>(Hb, scores, red2, Mpool);
  k_final<<<1, 256, 0, stream>>>(Mpool, Tpart, bt, Wcls, bcls, (float*)d_out);
}